// Round 6
// baseline (5252.644 us; speedup 1.0000x reference)
//
#include <hip/hip_runtime.h>

#define Hd 256
#define Wd 256
#define HW 65536
#define C 64
#define B 8
#define M 16
#define NDEPTH 4
#define NMLP 128

// ---------------- twiddle table: e^{2*pi*i*t/256}, double-precision accurate --------------
__global__ void k_table(float2* __restrict__ tab) {
    int t = threadIdx.x;
    double a = (6.283185307179586476925286766559 / 256.0) * (double)t;
    tab[t] = make_float2((float)cos(a), (float)sin(a));
}

// ---------------- fc0: 3 -> 64 channels, per pixel ----------------
__global__ void k_fc0(const float* __restrict__ x, const float* __restrict__ w,
                      const float* __restrict__ bias, float* __restrict__ h) {
    int p = blockIdx.x * 256 + threadIdx.x;   // 0 .. B*HW-1
    int b = p >> 16, pix = p & 65535;
    float x0 = x[(b * 3 + 0) * HW + pix];
    float x1 = x[(b * 3 + 1) * HW + pix];
    float x2 = x[(b * 3 + 2) * HW + pix];
    for (int o = 0; o < C; ++o) {
        float v = bias[o];
        v = fmaf(w[o * 3 + 0], x0, v);
        v = fmaf(w[o * 3 + 1], x1, v);
        v = fmaf(w[o * 3 + 2], x2, v);
        h[(b * C + o) * HW + pix] = v;
    }
}

// ---------------- forward DFT along y: T1[bc,ky,w] = sum_y h[bc,y,w] e^{-2pi i ky y/256} ---
__global__ __launch_bounds__(256, 2)
void k_fwd_y(const float* __restrict__ h, const float2* __restrict__ tab,
             float2* __restrict__ T1) {
    __shared__ float2 st[256];
    int bc = blockIdx.x;          // b*C+c
    int w = threadIdx.x;          // 0..255
    st[w] = tab[w];
    __syncthreads();
    const float* hp = h + bc * HW + w;
    float ar[M], ai[M];
#pragma unroll
    for (int k = 0; k < M; ++k) { ar[k] = 0.f; ai[k] = 0.f; }
    for (int y = 0; y < Hd; ++y) {
        float v = hp[y * Wd];
#pragma unroll
        for (int k = 0; k < M; ++k) {
            float2 e = st[(k * y) & 255];    // uniform LDS broadcast, in-order
            ar[k] = fmaf(v, e.x, ar[k]);
            ai[k] = fmaf(v, -e.y, ai[k]);
        }
    }
    float2* out = T1 + bc * (M * Wd) + w;
#pragma unroll
    for (int k = 0; k < M; ++k) out[k * Wd] = make_float2(ar[k], ai[k]);
}

// ---------------- forward DFT along x: X[bc, ky*16+kx] = sum_w T1[bc,ky,w] e^{-2pi i kx w/256}
__global__ __launch_bounds__(256, 2)
void k_fwd_x(const float2* __restrict__ T1, const float2* __restrict__ tab,
             float2* __restrict__ X) {
    __shared__ float2 sT[M * Wd];   // 32 KB
    __shared__ float2 st[256];      // 2 KB
    int bc = blockIdx.x, t = threadIdx.x;
    const float2* src = T1 + bc * (M * Wd);
#pragma unroll
    for (int j = 0; j < M; ++j) sT[j * 256 + t] = src[j * 256 + t];
    st[t] = tab[t];
    __syncthreads();
    int ky = t >> 4, kx = t & 15;
    float xr0 = 0.f, xi0 = 0.f, xr1 = 0.f, xi1 = 0.f;
    for (int w = 0; w < Wd; w += 2) {
        float2 Ta = sT[ky * 256 + w];
        float2 ea = st[(kx * w) & 255];
        xr0 = fmaf(Ta.x, ea.x, fmaf(Ta.y, ea.y, xr0));
        xi0 = fmaf(Ta.y, ea.x, fmaf(-Ta.x, ea.y, xi0));
        float2 Tb = sT[ky * 256 + w + 1];
        float2 eb = st[(kx * (w + 1)) & 255];
        xr1 = fmaf(Tb.x, eb.x, fmaf(Tb.y, eb.y, xr1));
        xi1 = fmaf(Tb.y, eb.x, fmaf(-Tb.x, eb.y, xi1));
    }
    X[bc * 256 + t] = make_float2(xr0 + xr1, xi0 + xi1);
}

// ---------------- mode mixing: Y[b,o,m] = sum_i X[b,i,m] * (wre+j*wim)[i,o,m] -------------
__global__ __launch_bounds__(256, 2)
void k_mix(const float2* __restrict__ X, const float* __restrict__ wre,
           const float* __restrict__ wim, float2* __restrict__ Y) {
    int o = blockIdx.x >> 2;   // 0..63
    int bq = blockIdx.x & 3;   // pair of batches
    int m = threadIdx.x;       // mode = ky*16+kx
    int b0 = bq * 2, b1 = bq * 2 + 1;
    float yr0 = 0.f, yi0 = 0.f, yr1 = 0.f, yi1 = 0.f;
    for (int i = 0; i < C; ++i) {
        float wr = wre[(i * C + o) * 256 + m];
        float wi = wim[(i * C + o) * 256 + m];
        float2 x0 = X[(b0 * C + i) * 256 + m];
        float2 x1 = X[(b1 * C + i) * 256 + m];
        yr0 = fmaf(x0.x, wr, fmaf(-x0.y, wi, yr0));
        yi0 = fmaf(x0.x, wi, fmaf(x0.y, wr, yi0));
        yr1 = fmaf(x1.x, wr, fmaf(-x1.y, wi, yr1));
        yi1 = fmaf(x1.x, wi, fmaf(x1.y, wr, yi1));
    }
    Y[(b0 * C + o) * 256 + m] = make_float2(yr0, yi0);
    Y[(b1 * C + o) * 256 + m] = make_float2(yr1, yi1);
}

// ---------------- inverse along y (with 1/(H*W) and Hermitian x2 folded in) ---------------
// G[bc, y, kx] = scale(kx) * sum_ky Y[bc, ky*16+kx] e^{+2pi i ky y/256}
__global__ __launch_bounds__(256, 2)
void k_inv_y(const float2* __restrict__ Y, const float2* __restrict__ tab,
             float2* __restrict__ G) {
    __shared__ float2 sY[256];
    __shared__ float2 st[256];
    int bc = blockIdx.x, t = threadIdx.x;   // t = y
    sY[t] = Y[bc * 256 + t];
    st[t] = tab[t];
    __syncthreads();
    float2 out[M];
#pragma unroll
    for (int kx = 0; kx < M; ++kx) {
        float gr = 0.f, gi = 0.f;
#pragma unroll
        for (int ky = 0; ky < M; ++ky) {
            float2 yv = sY[ky * 16 + kx];
            float2 e = st[(ky * t) & 255];
            gr = fmaf(yv.x, e.x, fmaf(-yv.y, e.y, gr));
            gi = fmaf(yv.x, e.y, fmaf(yv.y, e.x, gi));
        }
        float sc = (kx == 0 ? 1.0f : 2.0f) * (1.0f / 65536.0f);
        out[kx] = make_float2(gr * sc, gi * sc);
    }
    float2* gp = G + (bc * 256 + t) * M;
#pragma unroll
    for (int kx = 0; kx < M; ++kx) gp[kx] = out[kx];
}

// ---------------- fused: inverse along x + conv1x1 + add + relu, in-place on h ------------
// R1: (256,2) kills spill. R3/R5: sG+sW in LDS (pure-DS hot loop). R6: 2 y-rows per thread —
// hp[2][64] forces >=128 live VGPRs so the allocator can't squeeze to 7 waves/EU and
// serialize ds_read->wait->consume (R5 k_fc12 showed VGPR=68 register starvation); each
// weight ds_read_b128 now feeds 8 FMAs; per-pixel LDS instr count halves; 8 FMA chains.
// Rows share cs/sn (x-dependent only); only sG doubles (16 KB).
__global__ __launch_bounds__(256, 2)
void k_final(float* __restrict__ h, const float2* __restrict__ G,
             const float* __restrict__ ww, const float* __restrict__ wb,
             const float2* __restrict__ tab) {
    __shared__ float4 sW[C * 16];       // 16 KB: ww[o][i] as 16 float4 per o
    __shared__ float4 sG4[C * 2 * 8];   // 16 KB: [o][row][q] (q = pair of kx)
    __shared__ float2 st[256];          // 2 KB
    __shared__ float  sB[C];            // 256 B
    int by = blockIdx.x;                // 0..1023
    int b = by >> 7, y = (by & 127) * 2;
    int x = threadIdx.x;
    st[x] = tab[x];
    {   // stage ww: 1024 float4, coalesced
        const float4* wf4 = (const float4*)ww;
#pragma unroll
        for (int p = 0; p < 4; ++p) sW[x + p * 256] = wf4[x + p * 256];
    }
    if (x < C) sB[x] = wb[x];
    {   // stage G slices for rows y,y+1: 1024 float4; 8-thread groups fetch 128 B rows
        const float4* Gf4 = (const float4*)G;
#pragma unroll
        for (int p = 0; p < 4; ++p) {
            int f = x + p * 256;
            int o = f >> 4, r = (f >> 3) & 1, q = f & 7;
            sG4[f] = Gf4[((size_t)(b * C + o) * 256 + (y + r)) * 8 + q];
        }
    }
    __syncthreads();
    float cs[M], sn[M];
#pragma unroll
    for (int k = 0; k < M; ++k) {
        float2 e = st[(k * x) & 255];
        cs[k] = e.x; sn[k] = e.y;
    }
    float hp0[C], hp1[C];
    float* hb = h + b * C * HW + y * Wd + x;
#pragma unroll
    for (int i = 0; i < C; ++i) { hp0[i] = hb[i * HW]; hp1[i] = hb[i * HW + Wd]; }
    for (int o = 0; o < C; ++o) {
        float bias = sB[o];
        float a0 = bias, a1 = 0.f, a2 = 0.f, a3 = 0.f;
        float b0 = bias, b1v = 0.f, b2v = 0.f, b3 = 0.f;
#pragma unroll
        for (int c = 0; c < 16; ++c) {
            float4 wv = sW[o * 16 + c];      // broadcast ds_read_b128 feeds 8 FMAs
            a0 = fmaf(wv.x, hp0[4 * c + 0], a0);
            a1 = fmaf(wv.y, hp0[4 * c + 1], a1);
            a2 = fmaf(wv.z, hp0[4 * c + 2], a2);
            a3 = fmaf(wv.w, hp0[4 * c + 3], a3);
            b0 = fmaf(wv.x, hp1[4 * c + 0], b0);
            b1v = fmaf(wv.y, hp1[4 * c + 1], b1v);
            b2v = fmaf(wv.z, hp1[4 * c + 2], b2v);
            b3 = fmaf(wv.w, hp1[4 * c + 3], b3);
        }
#pragma unroll
        for (int q = 0; q < 8; ++q) {
            float4 g0 = sG4[o * 16 + q];         // row y:   (re,im,re,im) k=2q,2q+1
            a0 = fmaf(g0.x, cs[2 * q], a0);
            a1 = fmaf(-g0.y, sn[2 * q], a1);
            a2 = fmaf(g0.z, cs[2 * q + 1], a2);
            a3 = fmaf(-g0.w, sn[2 * q + 1], a3);
            float4 g1 = sG4[o * 16 + 8 + q];     // row y+1
            b0 = fmaf(g1.x, cs[2 * q], b0);
            b1v = fmaf(-g1.y, sn[2 * q], b1v);
            b2v = fmaf(g1.z, cs[2 * q + 1], b2v);
            b3 = fmaf(-g1.w, sn[2 * q + 1], b3);
        }
        hb[o * HW] = fmaxf((a0 + a1) + (a2 + a3), 0.0f);
        hb[o * HW + Wd] = fmaxf((b0 + b1v) + (b2v + b3), 0.0f);
    }
}

// ---------------- fused fc1 (relu) + fc2, per pixel ----------------
// R6: 2 y-rows per thread (same rationale as k_final — R5's VGPR=68 starvation).
__global__ __launch_bounds__(256, 2)
void k_fc12(const float* __restrict__ h, const float* __restrict__ w1,
            const float* __restrict__ b1, const float* __restrict__ w2,
            const float* __restrict__ b2, float* __restrict__ out) {
    __shared__ float4 sW1[NMLP * 16];   // 32 KB
    __shared__ float  sB1[NMLP];        // 512 B
    __shared__ float  sW2[3 * NMLP];    // 1.5 KB
    int by = blockIdx.x;                // 0..1023
    int b = by >> 7, y = (by & 127) * 2;
    int x = threadIdx.x;
    {   // stage w1: 2048 float4, coalesced
        const float4* wf4 = (const float4*)w1;
#pragma unroll
        for (int p = 0; p < 8; ++p) sW1[x + p * 256] = wf4[x + p * 256];
    }
    if (x < NMLP) sB1[x] = b1[x];
    sW2[x] = w2[x];
    if (x < 3 * NMLP - 256) sW2[256 + x] = w2[256 + x];
    __syncthreads();
    const float* hb = h + b * C * HW + y * Wd + x;
    float hp0[C], hp1[C];
#pragma unroll
    for (int i = 0; i < C; ++i) { hp0[i] = hb[i * HW]; hp1[i] = hb[i * HW + Wd]; }
    float a0 = b2[0], a1 = b2[1], a2 = b2[2];
    float d0 = b2[0], d1 = b2[1], d2 = b2[2];
    for (int m = 0; m < NMLP; ++m) {
        float bias = sB1[m];
        float c0 = bias, c1 = 0.f, c2 = 0.f, c3 = 0.f;
        float e0 = bias, e1 = 0.f, e2 = 0.f, e3 = 0.f;
#pragma unroll
        for (int c = 0; c < 16; ++c) {
            float4 wv = sW1[m * 16 + c];    // broadcast ds_read_b128 feeds 8 FMAs
            c0 = fmaf(wv.x, hp0[4 * c + 0], c0);
            c1 = fmaf(wv.y, hp0[4 * c + 1], c1);
            c2 = fmaf(wv.z, hp0[4 * c + 2], c2);
            c3 = fmaf(wv.w, hp0[4 * c + 3], c3);
            e0 = fmaf(wv.x, hp1[4 * c + 0], e0);
            e1 = fmaf(wv.y, hp1[4 * c + 1], e1);
            e2 = fmaf(wv.z, hp1[4 * c + 2], e2);
            e3 = fmaf(wv.w, hp1[4 * c + 3], e3);
        }
        float acc0 = fmaxf((c0 + c1) + (c2 + c3), 0.0f);
        float acc1 = fmaxf((e0 + e1) + (e2 + e3), 0.0f);
        float w20 = sW2[0 * NMLP + m], w21 = sW2[1 * NMLP + m], w22 = sW2[2 * NMLP + m];
        a0 = fmaf(w20, acc0, a0);
        a1 = fmaf(w21, acc0, a1);
        a2 = fmaf(w22, acc0, a2);
        d0 = fmaf(w20, acc1, d0);
        d1 = fmaf(w21, acc1, d1);
        d2 = fmaf(w22, acc1, d2);
    }
    float* ob = out + b * 3 * HW + y * Wd + x;
    ob[0] = a0;          ob[HW] = a1;          ob[2 * HW] = a2;
    ob[Wd] = d0;         ob[HW + Wd] = d1;     ob[2 * HW + Wd] = d2;
}

extern "C" void kernel_launch(void* const* d_in, const int* in_sizes, int n_in,
                              void* d_out, int out_size, void* d_ws, size_t ws_size,
                              hipStream_t stream) {
    const float* x     = (const float*)d_in[0];
    const float* fc0_w = (const float*)d_in[1];
    const float* fc0_b = (const float*)d_in[2];
    const float* swre  = (const float*)d_in[3];   // [4,64,64,16,16]
    const float* swim  = (const float*)d_in[4];
    const float* ww    = (const float*)d_in[5];   // [4,64,64]
    const float* wb    = (const float*)d_in[6];   // [4,64]
    const float* fc1w  = (const float*)d_in[7];
    const float* fc1b  = (const float*)d_in[8];
    const float* fc2w  = (const float*)d_in[9];
    const float* fc2b  = (const float*)d_in[10];

    float* ws = (float*)d_ws;
    float2* tab = (float2*)ws;                               // 512 floats
    float*  h   = ws + 512;                                  // 33,554,432 floats
    float2* T1  = (float2*)(ws + 512 + 33554432);            // 4,194,304 floats (doubles as G)
    float2* X   = (float2*)(ws + 512 + 33554432 + 4194304);  // 262,144 floats
    float2* Y   = (float2*)(ws + 512 + 33554432 + 4194304 + 262144); // 262,144 floats

    k_table<<<dim3(1), dim3(256), 0, stream>>>(tab);
    k_fc0<<<dim3(2048), dim3(256), 0, stream>>>(x, fc0_w, fc0_b, h);

    for (int d = 0; d < NDEPTH; ++d) {
        k_fwd_y<<<dim3(512), dim3(256), 0, stream>>>(h, tab, T1);
        k_fwd_x<<<dim3(512), dim3(256), 0, stream>>>(T1, tab, X);
        k_mix<<<dim3(256), dim3(256), 0, stream>>>(X, swre + (size_t)d * C * C * 256,
                                                   swim + (size_t)d * C * C * 256, Y);
        k_inv_y<<<dim3(512), dim3(256), 0, stream>>>(Y, tab, T1 /* reused as G */);
        k_final<<<dim3(1024), dim3(256), 0, stream>>>(h, T1, ww + d * C * C, wb + d * C, tab);
    }
    k_fc12<<<dim3(1024), dim3(256), 0, stream>>>(h, fc1w, fc1b, fc2w, fc2b, (float*)d_out);
}

// Round 7
// 5223.105 us; speedup vs baseline: 1.0057x; 1.0057x over previous
//
#include <hip/hip_runtime.h>

#define Hd 256
#define Wd 256
#define HW 65536
#define C 64
#define B 8
#define M 16
#define NDEPTH 4
#define NMLP 128

#define TIGHT_REGS __attribute__((amdgpu_flat_work_group_size(256, 256), amdgpu_waves_per_eu(2, 2)))

// ---------------- twiddle table: e^{2*pi*i*t/256}, double-precision accurate --------------
__global__ void k_table(float2* __restrict__ tab) {
    int t = threadIdx.x;
    double a = (6.283185307179586476925286766559 / 256.0) * (double)t;
    tab[t] = make_float2((float)cos(a), (float)sin(a));
}

// ---------------- fc0: 3 -> 64 channels, per pixel ----------------
__global__ void k_fc0(const float* __restrict__ x, const float* __restrict__ w,
                      const float* __restrict__ bias, float* __restrict__ h) {
    int p = blockIdx.x * 256 + threadIdx.x;   // 0 .. B*HW-1
    int b = p >> 16, pix = p & 65535;
    float x0 = x[(b * 3 + 0) * HW + pix];
    float x1 = x[(b * 3 + 1) * HW + pix];
    float x2 = x[(b * 3 + 2) * HW + pix];
    for (int o = 0; o < C; ++o) {
        float v = bias[o];
        v = fmaf(w[o * 3 + 0], x0, v);
        v = fmaf(w[o * 3 + 1], x1, v);
        v = fmaf(w[o * 3 + 2], x2, v);
        h[(b * C + o) * HW + pix] = v;
    }
}

// ---------------- forward DFT along y: T1[bc,ky,w] = sum_y h[bc,y,w] e^{-2pi i ky y/256} ---
__global__ __launch_bounds__(256, 2)
void k_fwd_y(const float* __restrict__ h, const float2* __restrict__ tab,
             float2* __restrict__ T1) {
    __shared__ float2 st[256];
    int bc = blockIdx.x;          // b*C+c
    int w = threadIdx.x;          // 0..255
    st[w] = tab[w];
    __syncthreads();
    const float* hp = h + bc * HW + w;
    float ar[M], ai[M];
#pragma unroll
    for (int k = 0; k < M; ++k) { ar[k] = 0.f; ai[k] = 0.f; }
    for (int y = 0; y < Hd; ++y) {
        float v = hp[y * Wd];
#pragma unroll
        for (int k = 0; k < M; ++k) {
            float2 e = st[(k * y) & 255];    // uniform LDS broadcast, in-order
            ar[k] = fmaf(v, e.x, ar[k]);
            ai[k] = fmaf(v, -e.y, ai[k]);
        }
    }
    float2* out = T1 + bc * (M * Wd) + w;
#pragma unroll
    for (int k = 0; k < M; ++k) out[k * Wd] = make_float2(ar[k], ai[k]);
}

// ---------------- forward DFT along x: X[bc, ky*16+kx] = sum_w T1[bc,ky,w] e^{-2pi i kx w/256}
__global__ __launch_bounds__(256, 2)
void k_fwd_x(const float2* __restrict__ T1, const float2* __restrict__ tab,
             float2* __restrict__ X) {
    __shared__ float2 sT[M * Wd];   // 32 KB
    __shared__ float2 st[256];      // 2 KB
    int bc = blockIdx.x, t = threadIdx.x;
    const float2* src = T1 + bc * (M * Wd);
#pragma unroll
    for (int j = 0; j < M; ++j) sT[j * 256 + t] = src[j * 256 + t];
    st[t] = tab[t];
    __syncthreads();
    int ky = t >> 4, kx = t & 15;
    float xr0 = 0.f, xi0 = 0.f, xr1 = 0.f, xi1 = 0.f;
    for (int w = 0; w < Wd; w += 2) {
        float2 Ta = sT[ky * 256 + w];
        float2 ea = st[(kx * w) & 255];
        xr0 = fmaf(Ta.x, ea.x, fmaf(Ta.y, ea.y, xr0));
        xi0 = fmaf(Ta.y, ea.x, fmaf(-Ta.x, ea.y, xi0));
        float2 Tb = sT[ky * 256 + w + 1];
        float2 eb = st[(kx * (w + 1)) & 255];
        xr1 = fmaf(Tb.x, eb.x, fmaf(Tb.y, eb.y, xr1));
        xi1 = fmaf(Tb.y, eb.x, fmaf(-Tb.x, eb.y, xi1));
    }
    X[bc * 256 + t] = make_float2(xr0 + xr1, xi0 + xi1);
}

// ---------------- mode mixing: Y[b,o,m] = sum_i X[b,i,m] * (wre+j*wim)[i,o,m] -------------
__global__ __launch_bounds__(256, 2)
void k_mix(const float2* __restrict__ X, const float* __restrict__ wre,
           const float* __restrict__ wim, float2* __restrict__ Y) {
    int o = blockIdx.x >> 2;   // 0..63
    int bq = blockIdx.x & 3;   // pair of batches
    int m = threadIdx.x;       // mode = ky*16+kx
    int b0 = bq * 2, b1 = bq * 2 + 1;
    float yr0 = 0.f, yi0 = 0.f, yr1 = 0.f, yi1 = 0.f;
    for (int i = 0; i < C; ++i) {
        float wr = wre[(i * C + o) * 256 + m];
        float wi = wim[(i * C + o) * 256 + m];
        float2 x0 = X[(b0 * C + i) * 256 + m];
        float2 x1 = X[(b1 * C + i) * 256 + m];
        yr0 = fmaf(x0.x, wr, fmaf(-x0.y, wi, yr0));
        yi0 = fmaf(x0.x, wi, fmaf(x0.y, wr, yi0));
        yr1 = fmaf(x1.x, wr, fmaf(-x1.y, wi, yr1));
        yi1 = fmaf(x1.x, wi, fmaf(x1.y, wr, yi1));
    }
    Y[(b0 * C + o) * 256 + m] = make_float2(yr0, yi0);
    Y[(b1 * C + o) * 256 + m] = make_float2(yr1, yi1);
}

// ---------------- inverse along y (with 1/(H*W) and Hermitian x2 folded in) ---------------
// G[bc, y, kx] = scale(kx) * sum_ky Y[bc, ky*16+kx] e^{+2pi i ky y/256}
__global__ __launch_bounds__(256, 2)
void k_inv_y(const float2* __restrict__ Y, const float2* __restrict__ tab,
             float2* __restrict__ G) {
    __shared__ float2 sY[256];
    __shared__ float2 st[256];
    int bc = blockIdx.x, t = threadIdx.x;   // t = y
    sY[t] = Y[bc * 256 + t];
    st[t] = tab[t];
    __syncthreads();
    float2 out[M];
#pragma unroll
    for (int kx = 0; kx < M; ++kx) {
        float gr = 0.f, gi = 0.f;
#pragma unroll
        for (int ky = 0; ky < M; ++ky) {
            float2 yv = sY[ky * 16 + kx];
            float2 e = st[(ky * t) & 255];
            gr = fmaf(yv.x, e.x, fmaf(-yv.y, e.y, gr));
            gi = fmaf(yv.x, e.y, fmaf(yv.y, e.x, gi));
        }
        float sc = (kx == 0 ? 1.0f : 2.0f) * (1.0f / 65536.0f);
        out[kx] = make_float2(gr * sc, gi * sc);
    }
    float2* gp = G + (bc * 256 + t) * M;
#pragma unroll
    for (int kx = 0; kx < M; ++kx) gp[kx] = out[kx];
}

// ---------------- fused: inverse along x + conv1x1 + add + relu, in-place on h ------------
// R3/R5: weights+G staged in LDS (hot loop = pure DS broadcast + FMA). Bottleneck model:
// at 1 px/thread the CU-shared LDS return pipe binds (24 b128/o vs 192 VALU cyc/o).
// R6: 2 y-rows/thread halves LDS reads per pixel BUT __launch_bounds__(256,2) let the
// allocator pick a 128-VGPR budget and spill hp1 (FETCH 74MB->1.9GB). R7: force the
// budget with amdgpu_waves_per_eu(2,2) — exactly 2 waves/EU, 256 VGPRs, no squeeze.
__global__ TIGHT_REGS
void k_final(float* __restrict__ h, const float2* __restrict__ G,
             const float* __restrict__ ww, const float* __restrict__ wb,
             const float2* __restrict__ tab) {
    __shared__ float4 sW[C * 16];       // 16 KB: ww[o][i] as 16 float4 per o
    __shared__ float4 sG4[C * 2 * 8];   // 16 KB: [o][row][q] (q = pair of kx)
    __shared__ float2 st[256];          // 2 KB
    __shared__ float  sB[C];            // 256 B
    int by = blockIdx.x;                // 0..1023
    int b = by >> 7, y = (by & 127) * 2;
    int x = threadIdx.x;
    st[x] = tab[x];
    {   // stage ww: 1024 float4, coalesced
        const float4* wf4 = (const float4*)ww;
#pragma unroll
        for (int p = 0; p < 4; ++p) sW[x + p * 256] = wf4[x + p * 256];
    }
    if (x < C) sB[x] = wb[x];
    {   // stage G slices for rows y,y+1: 1024 float4; 8-thread groups fetch 128 B rows
        const float4* Gf4 = (const float4*)G;
#pragma unroll
        for (int p = 0; p < 4; ++p) {
            int f = x + p * 256;
            int o = f >> 4, r = (f >> 3) & 1, q = f & 7;
            sG4[f] = Gf4[((size_t)(b * C + o) * 256 + (y + r)) * 8 + q];
        }
    }
    __syncthreads();
    float cs[M], sn[M];
#pragma unroll
    for (int k = 0; k < M; ++k) {
        float2 e = st[(k * x) & 255];
        cs[k] = e.x; sn[k] = e.y;
    }
    float hp0[C], hp1[C];
    float* hb = h + b * C * HW + y * Wd + x;
#pragma unroll
    for (int i = 0; i < C; ++i) { hp0[i] = hb[i * HW]; hp1[i] = hb[i * HW + Wd]; }
    for (int o = 0; o < C; ++o) {
        float bias = sB[o];
        float a0 = bias, a1 = 0.f, a2 = 0.f, a3 = 0.f;
        float b0 = bias, b1v = 0.f, b2v = 0.f, b3 = 0.f;
#pragma unroll
        for (int c = 0; c < 16; ++c) {
            float4 wv = sW[o * 16 + c];      // broadcast ds_read_b128 feeds 8 FMAs
            a0 = fmaf(wv.x, hp0[4 * c + 0], a0);
            a1 = fmaf(wv.y, hp0[4 * c + 1], a1);
            a2 = fmaf(wv.z, hp0[4 * c + 2], a2);
            a3 = fmaf(wv.w, hp0[4 * c + 3], a3);
            b0 = fmaf(wv.x, hp1[4 * c + 0], b0);
            b1v = fmaf(wv.y, hp1[4 * c + 1], b1v);
            b2v = fmaf(wv.z, hp1[4 * c + 2], b2v);
            b3 = fmaf(wv.w, hp1[4 * c + 3], b3);
        }
#pragma unroll
        for (int q = 0; q < 8; ++q) {
            float4 g0 = sG4[o * 16 + q];         // row y:   (re,im,re,im) k=2q,2q+1
            a0 = fmaf(g0.x, cs[2 * q], a0);
            a1 = fmaf(-g0.y, sn[2 * q], a1);
            a2 = fmaf(g0.z, cs[2 * q + 1], a2);
            a3 = fmaf(-g0.w, sn[2 * q + 1], a3);
            float4 g1 = sG4[o * 16 + 8 + q];     // row y+1
            b0 = fmaf(g1.x, cs[2 * q], b0);
            b1v = fmaf(-g1.y, sn[2 * q], b1v);
            b2v = fmaf(g1.z, cs[2 * q + 1], b2v);
            b3 = fmaf(-g1.w, sn[2 * q + 1], b3);
        }
        hb[o * HW] = fmaxf((a0 + a1) + (a2 + a3), 0.0f);
        hb[o * HW + Wd] = fmaxf((b0 + b1v) + (b2v + b3), 0.0f);
    }
}

// ---------------- fused fc1 (relu) + fc2, 2 pixels per thread ----------------
// R7: same forced-budget fix as k_final.
__global__ TIGHT_REGS
void k_fc12(const float* __restrict__ h, const float* __restrict__ w1,
            const float* __restrict__ b1, const float* __restrict__ w2,
            const float* __restrict__ b2, float* __restrict__ out) {
    __shared__ float4 sW1[NMLP * 16];   // 32 KB
    __shared__ float  sB1[NMLP];        // 512 B
    __shared__ float  sW2[3 * NMLP];    // 1.5 KB
    int by = blockIdx.x;                // 0..1023
    int b = by >> 7, y = (by & 127) * 2;
    int x = threadIdx.x;
    {   // stage w1: 2048 float4, coalesced
        const float4* wf4 = (const float4*)w1;
#pragma unroll
        for (int p = 0; p < 8; ++p) sW1[x + p * 256] = wf4[x + p * 256];
    }
    if (x < NMLP) sB1[x] = b1[x];
    sW2[x] = w2[x];
    if (x < 3 * NMLP - 256) sW2[256 + x] = w2[256 + x];
    __syncthreads();
    const float* hb = h + b * C * HW + y * Wd + x;
    float hp0[C], hp1[C];
#pragma unroll
    for (int i = 0; i < C; ++i) { hp0[i] = hb[i * HW]; hp1[i] = hb[i * HW + Wd]; }
    float a0 = b2[0], a1 = b2[1], a2 = b2[2];
    float d0 = b2[0], d1 = b2[1], d2 = b2[2];
    for (int m = 0; m < NMLP; ++m) {
        float bias = sB1[m];
        float c0 = bias, c1 = 0.f, c2 = 0.f, c3 = 0.f;
        float e0 = bias, e1 = 0.f, e2 = 0.f, e3 = 0.f;
#pragma unroll
        for (int c = 0; c < 16; ++c) {
            float4 wv = sW1[m * 16 + c];    // broadcast ds_read_b128 feeds 8 FMAs
            c0 = fmaf(wv.x, hp0[4 * c + 0], c0);
            c1 = fmaf(wv.y, hp0[4 * c + 1], c1);
            c2 = fmaf(wv.z, hp0[4 * c + 2], c2);
            c3 = fmaf(wv.w, hp0[4 * c + 3], c3);
            e0 = fmaf(wv.x, hp1[4 * c + 0], e0);
            e1 = fmaf(wv.y, hp1[4 * c + 1], e1);
            e2 = fmaf(wv.z, hp1[4 * c + 2], e2);
            e3 = fmaf(wv.w, hp1[4 * c + 3], e3);
        }
        float acc0 = fmaxf((c0 + c1) + (c2 + c3), 0.0f);
        float acc1 = fmaxf((e0 + e1) + (e2 + e3), 0.0f);
        float w20 = sW2[0 * NMLP + m], w21 = sW2[1 * NMLP + m], w22 = sW2[2 * NMLP + m];
        a0 = fmaf(w20, acc0, a0);
        a1 = fmaf(w21, acc0, a1);
        a2 = fmaf(w22, acc0, a2);
        d0 = fmaf(w20, acc1, d0);
        d1 = fmaf(w21, acc1, d1);
        d2 = fmaf(w22, acc1, d2);
    }
    float* ob = out + b * 3 * HW + y * Wd + x;
    ob[0] = a0;          ob[HW] = a1;          ob[2 * HW] = a2;
    ob[Wd] = d0;         ob[HW + Wd] = d1;     ob[2 * HW + Wd] = d2;
}

extern "C" void kernel_launch(void* const* d_in, const int* in_sizes, int n_in,
                              void* d_out, int out_size, void* d_ws, size_t ws_size,
                              hipStream_t stream) {
    const float* x     = (const float*)d_in[0];
    const float* fc0_w = (const float*)d_in[1];
    const float* fc0_b = (const float*)d_in[2];
    const float* swre  = (const float*)d_in[3];   // [4,64,64,16,16]
    const float* swim  = (const float*)d_in[4];
    const float* ww    = (const float*)d_in[5];   // [4,64,64]
    const float* wb    = (const float*)d_in[6];   // [4,64]
    const float* fc1w  = (const float*)d_in[7];
    const float* fc1b  = (const float*)d_in[8];
    const float* fc2w  = (const float*)d_in[9];
    const float* fc2b  = (const float*)d_in[10];

    float* ws = (float*)d_ws;
    float2* tab = (float2*)ws;                               // 512 floats
    float*  h   = ws + 512;                                  // 33,554,432 floats
    float2* T1  = (float2*)(ws + 512 + 33554432);            // 4,194,304 floats (doubles as G)
    float2* X   = (float2*)(ws + 512 + 33554432 + 4194304);  // 262,144 floats
    float2* Y   = (float2*)(ws + 512 + 33554432 + 4194304 + 262144); // 262,144 floats

    k_table<<<dim3(1), dim3(256), 0, stream>>>(tab);
    k_fc0<<<dim3(2048), dim3(256), 0, stream>>>(x, fc0_w, fc0_b, h);

    for (int d = 0; d < NDEPTH; ++d) {
        k_fwd_y<<<dim3(512), dim3(256), 0, stream>>>(h, tab, T1);
        k_fwd_x<<<dim3(512), dim3(256), 0, stream>>>(T1, tab, X);
        k_mix<<<dim3(256), dim3(256), 0, stream>>>(X, swre + (size_t)d * C * C * 256,
                                                   swim + (size_t)d * C * C * 256, Y);
        k_inv_y<<<dim3(512), dim3(256), 0, stream>>>(Y, tab, T1 /* reused as G */);
        k_final<<<dim3(1024), dim3(256), 0, stream>>>(h, T1, ww + d * C * C, wb + d * C, tab);
    }
    k_fc12<<<dim3(1024), dim3(256), 0, stream>>>(h, fc1w, fc1b, fc2w, fc2b, (float*)d_out);
}